// Round 15
// baseline (2252.322 us; speedup 1.0000x reference)
//
#include <hip/hip_runtime.h>

#define NN 100000
#define NE 1600000
#define NG 1024
#define NODE_IN 163
#define SLOPE 0.01f
#define NBUK 391
#define BUKSH 8
#define EPB 8192
#define NBLK ((NE + EPB - 1) / EPB)

typedef short s16x8 __attribute__((ext_vector_type(8)));
typedef float f32x4 __attribute__((ext_vector_type(4)));

__device__ __forceinline__ unsigned short bf16_rne(float x) {
  unsigned u = __float_as_uint(x);
  return (unsigned short)((u + 0x7FFFu + ((u >> 16) & 1u)) >> 16);
}
__device__ __forceinline__ float bf16_f32(unsigned short h) {
  return __uint_as_float(((unsigned)h) << 16);
}

// ---------------- bucket build (privatized counting sort; rounds 4-14, verified) ------
__global__ void k_hist(const int* __restrict__ dst, int* __restrict__ bh, int E) {
  __shared__ int h[NBUK];
  for (int i = threadIdx.x; i < NBUK; i += 256) h[i] = 0;
  __syncthreads();
  int beg = blockIdx.x * EPB, end = min(E, beg + EPB);
  for (int e = beg + threadIdx.x; e < end; e += 256) atomicAdd(&h[dst[e] >> BUKSH], 1);
  __syncthreads();
  for (int i = threadIdx.x; i < NBUK; i += 256) bh[blockIdx.x * NBUK + i] = h[i];
}

__global__ void k_bucket_scan(int* __restrict__ bh, int* __restrict__ btot) {
  __shared__ int s[256];
  int bucket = blockIdx.x, tid = threadIdx.x;
  int v = (tid < NBLK) ? bh[tid * NBUK + bucket] : 0;
  s[tid] = v;
  __syncthreads();
  for (int off = 1; off < 256; off <<= 1) {
    int t = (tid >= off) ? s[tid - off] : 0;
    __syncthreads();
    s[tid] += t;
    __syncthreads();
  }
  if (tid < NBLK) bh[tid * NBUK + bucket] = s[tid] - v;
  if (tid == 255) btot[bucket] = s[255];
}

__global__ void k_btot_scan(const int* __restrict__ btot, int* __restrict__ boffs, int E) {
  __shared__ int s[512];
  int tid = threadIdx.x;
  int v = (tid < NBUK) ? btot[tid] : 0;
  s[tid] = v;
  __syncthreads();
  for (int off = 1; off < 512; off <<= 1) {
    int t = (tid >= off) ? s[tid - off] : 0;
    __syncthreads();
    s[tid] += t;
    __syncthreads();
  }
  if (tid < NBUK) boffs[tid] = s[tid] - v;
  if (tid == 0) boffs[NBUK] = E;
}

__global__ void k_scatter(const int* __restrict__ src, const int* __restrict__ dst,
                          const int* __restrict__ bh, const int* __restrict__ boffs,
                          unsigned* __restrict__ bedge, int E) {
  __shared__ int cur[NBUK];
  for (int i = threadIdx.x; i < NBUK; i += 256)
    cur[i] = boffs[i] + bh[blockIdx.x * NBUK + i];
  __syncthreads();
  int beg = blockIdx.x * EPB, end = min(E, beg + EPB);
  for (int e = beg + threadIdx.x; e < end; e += 256) {
    int d = dst[e];
    int pos = atomicAdd(&cur[d >> BUKSH], 1);
    bedge[pos] = (unsigned)src[e] | ((unsigned)(d & 255) << 17);
  }
}

// degree -> dis only (csr scatter no longer needed; agg consumes bedge directly)
__global__ void k_deg(const unsigned* __restrict__ bedge, const int* __restrict__ boffs,
                      float* __restrict__ dis, int N) {
  __shared__ int lcnt[256];
  int b = blockIdx.x, tid = threadIdx.x;
  lcnt[tid] = 0;
  __syncthreads();
  int beg = boffs[b], end = boffs[b + 1];
  for (int e = beg + tid; e < end; e += 256) atomicAdd(&lcnt[bedge[e] >> 17], 1);
  __syncthreads();
  int node = (b << BUKSH) + tid;
  if (node < N) dis[node] = rsqrtf((float)(lcnt[tid] + 1));
}

// ---------------- W pre-split: W[K][64] fp32 -> Wt_hi/lo[64][KP] bf16 (transposed) ----
__global__ void k_wsplit(const float* __restrict__ W, short* __restrict__ hi,
                         short* __restrict__ lo, int K, int KP) {
  int idx = blockIdx.x * 256 + threadIdx.x;
  if (idx >= 64 * KP) return;
  int c = idx / KP, kk = idx - c * KP;
  float v = (kk < K) ? W[(size_t)kk * 64 + c] : 0.f;
  unsigned short h = bf16_rne(v);
  hi[idx] = (short)h;
  lo[idx] = (short)bf16_rne(v - bf16_f32(h));
}

// ---------------- GEMM via MFMA split-bf16; output bf16 rows (consumed by agg) --------
template<int K, int KP>
__launch_bounds__(256)
__global__ void k_gemm(const float* __restrict__ X, const short* __restrict__ Whi,
                       const short* __restrict__ Wlo, const float* __restrict__ disv,
                       unsigned short* __restrict__ Y, int N) {
  constexpr int KC = KP / 32;
  constexpr int PA = 40;
  constexpr int PB = 40;
  __shared__ __align__(16) short sAh[2][128 * PA];
  __shared__ __align__(16) short sAl[2][128 * PA];
  __shared__ __align__(16) short sBh[2][64 * PB];
  __shared__ __align__(16) short sBl[2][64 * PB];

  const int tid = threadIdx.x;
  const int lane = tid & 63, wv = tid >> 6;
  const int l15 = lane & 15, l4 = lane >> 4;
  const int gbase = blockIdx.x << 7;

  const int arow = tid >> 1, akh = (tid & 1) << 4;
  int grow = gbase + arow;
  if (K != KP) grow = min(grow, N - 1);
  const float* xr = X + (size_t)grow * K;
  const int bcol = tid >> 2, bk8 = (tid & 3) << 3;

  float4 ra0, ra1, ra2, ra3;
  s16x8 rbh, rbl;

  auto loadA = [&](int c) {
    if (K != KP && c == KC - 1) {
      ra0 = ra1 = ra2 = ra3 = make_float4(0.f, 0.f, 0.f, 0.f);
      if (akh == 0) { ra0.x = xr[160]; ra0.y = xr[161]; ra0.z = xr[162]; }
    } else {
      const float* p = xr + c * 32 + akh;
      ra0 = *(const float4*)(p);
      ra1 = *(const float4*)(p + 4);
      ra2 = *(const float4*)(p + 8);
      ra3 = *(const float4*)(p + 12);
    }
  };
  auto loadB = [&](int c) {
    const size_t o = (size_t)bcol * KP + c * 32 + bk8;
    rbh = *(const s16x8*)(Whi + o);
    rbl = *(const s16x8*)(Wlo + o);
  };
  auto writeLDS = [&](int b) {
    short hb[16], lb[16];
    float v[16] = {ra0.x, ra0.y, ra0.z, ra0.w, ra1.x, ra1.y, ra1.z, ra1.w,
                   ra2.x, ra2.y, ra2.z, ra2.w, ra3.x, ra3.y, ra3.z, ra3.w};
    #pragma unroll
    for (int j = 0; j < 16; ++j) {
      unsigned short h = bf16_rne(v[j]);
      hb[j] = (short)h;
      lb[j] = (short)bf16_rne(v[j] - bf16_f32(h));
    }
    short* ah = sAh[b] + arow * PA + akh;
    *(s16x8*)(ah) = *(const s16x8*)(hb);
    *(s16x8*)(ah + 8) = *(const s16x8*)(hb + 8);
    short* al = sAl[b] + arow * PA + akh;
    *(s16x8*)(al) = *(const s16x8*)(lb);
    *(s16x8*)(al + 8) = *(const s16x8*)(lb + 8);
    *(s16x8*)(sBh[b] + bcol * PB + bk8) = rbh;
    *(s16x8*)(sBl[b] + bcol * PB + bk8) = rbl;
  };

  f32x4 acc[2][4];
  #pragma unroll
  for (int rt = 0; rt < 2; ++rt)
    #pragma unroll
    for (int ct = 0; ct < 4; ++ct) acc[rt][ct] = (f32x4){0.f, 0.f, 0.f, 0.f};

  loadA(0); loadB(0); writeLDS(0);
  __syncthreads();

  #pragma unroll 1
  for (int c = 0; c < KC; ++c) {
    if (c + 1 < KC) { loadA(c + 1); loadB(c + 1); }   // issue early (T14)
    const int b = c & 1;
    const int aoff0 = (wv * 32 + l15) * PA + l4 * 8;
    const int aoff1 = aoff0 + 16 * PA;
    s16x8 a0h = *(const s16x8*)(sAh[b] + aoff0);
    s16x8 a0l = *(const s16x8*)(sAl[b] + aoff0);
    s16x8 a1h = *(const s16x8*)(sAh[b] + aoff1);
    s16x8 a1l = *(const s16x8*)(sAl[b] + aoff1);
    #pragma unroll
    for (int ct = 0; ct < 4; ++ct) {
      const int boff = (ct * 16 + l15) * PB + l4 * 8;
      s16x8 bh = *(const s16x8*)(sBh[b] + boff);
      s16x8 bl = *(const s16x8*)(sBl[b] + boff);
      acc[0][ct] = __builtin_amdgcn_mfma_f32_16x16x32_bf16(a0h, bh, acc[0][ct], 0, 0, 0);
      acc[0][ct] = __builtin_amdgcn_mfma_f32_16x16x32_bf16(a0l, bh, acc[0][ct], 0, 0, 0);
      acc[0][ct] = __builtin_amdgcn_mfma_f32_16x16x32_bf16(a0h, bl, acc[0][ct], 0, 0, 0);
      acc[1][ct] = __builtin_amdgcn_mfma_f32_16x16x32_bf16(a1h, bh, acc[1][ct], 0, 0, 0);
      acc[1][ct] = __builtin_amdgcn_mfma_f32_16x16x32_bf16(a1l, bh, acc[1][ct], 0, 0, 0);
      acc[1][ct] = __builtin_amdgcn_mfma_f32_16x16x32_bf16(a1h, bl, acc[1][ct], 0, 0, 0);
    }
    if (c + 1 < KC) { writeLDS((c + 1) & 1); __syncthreads(); }
  }

  const int rb = gbase + wv * 32;
  #pragma unroll
  for (int rt = 0; rt < 2; ++rt) {
    #pragma unroll
    for (int j = 0; j < 4; ++j) {
      int row = rb + rt * 16 + l4 * 4 + j;
      if (row < N) {
        float d = disv[row];
        unsigned short* yp = Y + ((size_t)row << 6) + l15;
        yp[0]  = bf16_rne(acc[rt][0][j] * d);
        yp[16] = bf16_rne(acc[rt][1][j] * d);
        yp[32] = bf16_rne(acc[rt][2][j] * d);
        yp[48] = bf16_rne(acc[rt][3][j] * d);
      }
    }
  }
}

// ---------------- agg: bucket-resident LDS accumulation over bedge --------------------
// One block per 256-node bucket; 64KB fp32 accumulators in LDS (2 blk/CU).
// Edge-parallel: each wave takes 16-edge chunks round-robin; per edge: uniform bedge
// load -> bf16 row gather (128B/wave, 16 independent in flight) -> ds_add_f32
// (2-way bank alias, free). Long-lived waves with deep MLP replace round-14's
// one-node-per-wave serial chains (latency-bound at 56us).
__launch_bounds__(256)
__global__ void k_agg(const unsigned* __restrict__ bedge, const int* __restrict__ boffs,
                      const unsigned short* __restrict__ G, const float* __restrict__ dis,
                      const float* __restrict__ bias, float* __restrict__ H, int N) {
  __shared__ float lacc[256 * 64];
  const int tid = threadIdx.x;
  const int lane = tid & 63, wv = tid >> 6;
  const int b = blockIdx.x;
  {
    f32x4 z = {0.f, 0.f, 0.f, 0.f};
    f32x4* p = (f32x4*)lacc;
    #pragma unroll
    for (int i = 0; i < 16; ++i) p[tid + 256 * i] = z;
  }
  __syncthreads();

  const int beg = boffs[b], end = boffs[b + 1];
  int e0 = beg + wv * 16;
  for (; e0 + 16 <= end; e0 += 64) {
    unsigned w[16];
    #pragma unroll
    for (int j = 0; j < 16; ++j) w[j] = bedge[e0 + j];
    float g[16];
    #pragma unroll
    for (int j = 0; j < 16; ++j)
      g[j] = bf16_f32(G[((size_t)(w[j] & 0x1FFFFu) << 6) + lane]);
    #pragma unroll
    for (int j = 0; j < 16; ++j)
      atomicAdd(&lacc[((w[j] >> 17) << 6) + lane], g[j]);
  }
  for (int e = e0; e < min(e0 + 16, end); ++e) {
    unsigned w = bedge[e];
    float g = bf16_f32(G[((size_t)(w & 0x1FFFFu) << 6) + lane]);
    atomicAdd(&lacc[((w >> 17) << 6) + lane], g);
  }
  __syncthreads();

  #pragma unroll 1
  for (int n = wv; n < 256; n += 4) {
    int node = (b << BUKSH) + n;
    if (node < N) {
      float acc = lacc[(n << 6) + lane] + bf16_f32(G[((size_t)node << 6) + lane]);
      acc = acc * dis[node] + bias[lane];
      H[((size_t)node << 6) + lane] = (acc > 0.f) ? acc : SLOPE * acc;
    }
  }
}

// One wave per graph: mean-pool + fc1 + lrelu + fc2
__launch_bounds__(64)
__global__ void k_pool(const float* __restrict__ H, const int* __restrict__ batch,
                       const float* __restrict__ f1W, const float* __restrict__ f1b,
                       const float* __restrict__ f2W, const float* __restrict__ f2b,
                       float* __restrict__ out, int N) {
  int g = blockIdx.x;
  int lane = threadIdx.x;
  int lo = 0, hi = N;
  while (lo < hi) { int m = (lo + hi) >> 1; if (batch[m] < g) lo = m + 1; else hi = m; }
  int beg = lo;
  hi = N;
  while (lo < hi) { int m = (lo + hi) >> 1; if (batch[m] < g + 1) lo = m + 1; else hi = m; }
  int end = lo;
  float acc = 0.f;
  for (int r = beg; r < end; ++r) acc += H[(size_t)r * 64 + lane];
  float c = (float)(end - beg);
  acc /= (c < 1.f ? 1.f : c);
  __shared__ float p[64];
  p[lane] = acc;
  __syncthreads();
  float q = f1b[lane];
  #pragma unroll
  for (int k = 0; k < 64; ++k) q += p[k] * f1W[k * 64 + lane];
  q = (q > 0.f) ? q : SLOPE * q;
  float v = q * f2W[lane];
  #pragma unroll
  for (int off = 32; off > 0; off >>= 1) v += __shfl_down(v, off, 64);
  if (lane == 0) out[g] = v + f2b[0];
}

extern "C" void kernel_launch(void* const* d_in, const int* in_sizes, int n_in,
                              void* d_out, int out_size, void* d_ws, size_t ws_size,
                              hipStream_t stream) {
  const float* x    = (const float*)d_in[0];
  const int*  eidx  = (const int*)d_in[1];
  const int*  batch = (const int*)d_in[2];
  const float* W0 = (const float*)d_in[3];
  const float* b0 = (const float*)d_in[4];
  const float* W1 = (const float*)d_in[5];
  const float* b1 = (const float*)d_in[6];
  const float* W2 = (const float*)d_in[7];
  const float* b2 = (const float*)d_in[8];
  const float* f1W = (const float*)d_in[9];
  const float* f1b = (const float*)d_in[10];
  const float* f2W = (const float*)d_in[11];
  const float* f2b = (const float*)d_in[12];
  float* out = (float*)d_out;

  const int N = NN, E = NE;
  const int* src  = eidx;
  const int* dstp = eidx + E;

  const size_t NPAD = 100096;   // 782*128 rows exactly
  char* w = (char*)d_ws;
  float* H     = (float*)w; w += NPAD * 64 * 4;                // fp32 layer buffer
  unsigned short* G = (unsigned short*)w; w += NPAD * 64 * 2;  // bf16 gemm output
  unsigned* bedge = (unsigned*)w; w += (size_t)E * 4;          // bucket-grouped edges
  float* dis   = (float*)w; w += (size_t)N * 4;
  int*   bh    = (int*)w;   w += (size_t)NBLK * NBUK * 4;
  int*   btot  = (int*)w;   w += (NBUK + 1) * 4;
  int*   boffs = (int*)w;   w += (NBUK + 4) * 4;
  short* wt0h  = (short*)w; w += 64 * 192 * 2;
  short* wt0l  = (short*)w; w += 64 * 192 * 2;
  short* wt1h  = (short*)w; w += 64 * 64 * 2;
  short* wt1l  = (short*)w; w += 64 * 64 * 2;
  short* wt2h  = (short*)w; w += 64 * 64 * 2;
  short* wt2l  = (short*)w; w += 64 * 64 * 2;

  k_wsplit<<<48, 256, 0, stream>>>(W0, wt0h, wt0l, NODE_IN, 192);
  k_wsplit<<<16, 256, 0, stream>>>(W1, wt1h, wt1l, 64, 64);
  k_wsplit<<<16, 256, 0, stream>>>(W2, wt2h, wt2l, 64, 64);

  k_hist<<<NBLK, 256, 0, stream>>>(dstp, bh, E);
  k_bucket_scan<<<NBUK, 256, 0, stream>>>(bh, btot);
  k_btot_scan<<<1, 512, 0, stream>>>(btot, boffs, E);
  k_scatter<<<NBLK, 256, 0, stream>>>(src, dstp, bh, boffs, bedge, E);
  k_deg<<<NBUK, 256, 0, stream>>>(bedge, boffs, dis, N);

  const int NTB = (N + 127) / 128;   // 782
  k_gemm<NODE_IN, 192><<<NTB, 256, 0, stream>>>(x, wt0h, wt0l, dis, G, N);
  k_agg<<<NBUK, 256, 0, stream>>>(bedge, boffs, G, dis, b0, H, N);
  k_gemm<64, 64><<<NTB, 256, 0, stream>>>(H, wt1h, wt1l, dis, G, N);
  k_agg<<<NBUK, 256, 0, stream>>>(bedge, boffs, G, dis, b1, H, N);
  k_gemm<64, 64><<<NTB, 256, 0, stream>>>(H, wt2h, wt2l, dis, G, N);
  k_agg<<<NBUK, 256, 0, stream>>>(bedge, boffs, G, dis, b2, H, N);
  k_pool<<<NG, 64, 0, stream>>>(H, batch, f1W, f1b, f2W, f2b, out, N);
}

// Round 16
// 348.046 us; speedup vs baseline: 6.4713x; 6.4713x over previous
//
#include <hip/hip_runtime.h>

#define NN 100000
#define NE 1600000
#define NG 1024
#define NODE_IN 163
#define SLOPE 0.01f
#define NBUK 391
#define BUKSH 8
#define EPB 8192
#define NBLK ((NE + EPB - 1) / EPB)

typedef short s16x8 __attribute__((ext_vector_type(8)));
typedef float f32x4 __attribute__((ext_vector_type(4)));

__device__ __forceinline__ unsigned short bf16_rne(float x) {
  unsigned u = __float_as_uint(x);
  return (unsigned short)((u + 0x7FFFu + ((u >> 16) & 1u)) >> 16);
}
__device__ __forceinline__ float bf16_f32(unsigned short h) {
  return __uint_as_float(((unsigned)h) << 16);
}

// ---------------- CSR build (privatized counting sort; rounds 4-14, verified) ---------
__global__ void k_hist(const int* __restrict__ dst, int* __restrict__ bh, int E) {
  __shared__ int h[NBUK];
  for (int i = threadIdx.x; i < NBUK; i += 256) h[i] = 0;
  __syncthreads();
  int beg = blockIdx.x * EPB, end = min(E, beg + EPB);
  for (int e = beg + threadIdx.x; e < end; e += 256) atomicAdd(&h[dst[e] >> BUKSH], 1);
  __syncthreads();
  for (int i = threadIdx.x; i < NBUK; i += 256) bh[blockIdx.x * NBUK + i] = h[i];
}

__global__ void k_bucket_scan(int* __restrict__ bh, int* __restrict__ btot) {
  __shared__ int s[256];
  int bucket = blockIdx.x, tid = threadIdx.x;
  int v = (tid < NBLK) ? bh[tid * NBUK + bucket] : 0;
  s[tid] = v;
  __syncthreads();
  for (int off = 1; off < 256; off <<= 1) {
    int t = (tid >= off) ? s[tid - off] : 0;
    __syncthreads();
    s[tid] += t;
    __syncthreads();
  }
  if (tid < NBLK) bh[tid * NBUK + bucket] = s[tid] - v;
  if (tid == 255) btot[bucket] = s[255];
}

__global__ void k_btot_scan(const int* __restrict__ btot, int* __restrict__ boffs, int E) {
  __shared__ int s[512];
  int tid = threadIdx.x;
  int v = (tid < NBUK) ? btot[tid] : 0;
  s[tid] = v;
  __syncthreads();
  for (int off = 1; off < 512; off <<= 1) {
    int t = (tid >= off) ? s[tid - off] : 0;
    __syncthreads();
    s[tid] += t;
    __syncthreads();
  }
  if (tid < NBUK) boffs[tid] = s[tid] - v;
  if (tid == 0) boffs[NBUK] = E;
}

__global__ void k_scatter(const int* __restrict__ src, const int* __restrict__ dst,
                          const int* __restrict__ bh, const int* __restrict__ boffs,
                          unsigned* __restrict__ bedge, int E) {
  __shared__ int cur[NBUK];
  for (int i = threadIdx.x; i < NBUK; i += 256)
    cur[i] = boffs[i] + bh[blockIdx.x * NBUK + i];
  __syncthreads();
  int beg = blockIdx.x * EPB, end = min(E, beg + EPB);
  for (int e = beg + threadIdx.x; e < end; e += 256) {
    int d = dst[e];
    int pos = atomicAdd(&cur[d >> BUKSH], 1);
    bedge[pos] = (unsigned)src[e] | ((unsigned)(d & 255) << 17);
  }
}

__global__ void k_b2csr(const unsigned* __restrict__ bedge, const int* __restrict__ boffs,
                        int* __restrict__ offs, float* __restrict__ dis,
                        int* __restrict__ csr, int N) {
  __shared__ int lcnt[256];
  __shared__ int s[256];
  __shared__ int lcur[256];
  int b = blockIdx.x, tid = threadIdx.x;
  int beg = boffs[b], end = boffs[b + 1];
  lcnt[tid] = 0;
  __syncthreads();
  for (int e = beg + tid; e < end; e += 256) atomicAdd(&lcnt[bedge[e] >> 17], 1);
  __syncthreads();
  int v = lcnt[tid];
  s[tid] = v;
  __syncthreads();
  for (int off = 1; off < 256; off <<= 1) {
    int t = (tid >= off) ? s[tid - off] : 0;
    __syncthreads();
    s[tid] += t;
    __syncthreads();
  }
  int o = s[tid] - v;
  int node = (b << BUKSH) + tid;
  if (node <= N) offs[node] = beg + o;
  if (node < N) dis[node] = rsqrtf((float)(v + 1));
  lcur[tid] = o;
  __syncthreads();
  for (int e = beg + tid; e < end; e += 256) {
    unsigned w = bedge[e];
    int p = atomicAdd(&lcur[w >> 17], 1);
    csr[beg + p] = (int)(w & 0x1FFFFu);
  }
}

// ---------------- W pre-split: W[K][64] fp32 -> Wt_hi/lo[64][KP] bf16 (transposed) ----
__global__ void k_wsplit(const float* __restrict__ W, short* __restrict__ hi,
                         short* __restrict__ lo, int K, int KP) {
  int idx = blockIdx.x * 256 + threadIdx.x;
  if (idx >= 64 * KP) return;
  int c = idx / KP, kk = idx - c * KP;
  float v = (kk < K) ? W[(size_t)kk * 64 + c] : 0.f;
  unsigned short h = bf16_rne(v);
  hi[idx] = (short)h;
  lo[idx] = (short)bf16_rne(v - bf16_f32(h));
}

// ---------------- GEMM via MFMA split-bf16; B read direct from global (L2-resident) ---
// LDS = A staging only (40KB dbuf -> 4 blk/CU; was 60KB/2 blk with B staged).
template<int K, int KP>
__launch_bounds__(256)
__global__ void k_gemm(const float* __restrict__ X, const short* __restrict__ Whi,
                       const short* __restrict__ Wlo, const float* __restrict__ disv,
                       unsigned short* __restrict__ Y, int N) {
  constexpr int KC = KP / 32;
  constexpr int PA = 40;
  __shared__ __align__(16) short sAh[2][128 * PA];
  __shared__ __align__(16) short sAl[2][128 * PA];

  const int tid = threadIdx.x;
  const int lane = tid & 63, wv = tid >> 6;
  const int l15 = lane & 15, l4 = lane >> 4;
  const int gbase = blockIdx.x << 7;

  const int arow = tid >> 1, akh = (tid & 1) << 4;
  int grow = gbase + arow;
  if (K != KP) grow = min(grow, N - 1);
  const float* xr = X + (size_t)grow * K;
  const int wb = l15 * KP + l4 * 8;     // lane-fixed B offset

  float4 ra0, ra1, ra2, ra3;

  auto loadA = [&](int c) {
    if (K != KP && c == KC - 1) {
      ra0 = ra1 = ra2 = ra3 = make_float4(0.f, 0.f, 0.f, 0.f);
      if (akh == 0) { ra0.x = xr[160]; ra0.y = xr[161]; ra0.z = xr[162]; }
    } else {
      const float* p = xr + c * 32 + akh;
      ra0 = *(const float4*)(p);
      ra1 = *(const float4*)(p + 4);
      ra2 = *(const float4*)(p + 8);
      ra3 = *(const float4*)(p + 12);
    }
  };
  auto writeLDS = [&](int b) {
    short hb[16], lb[16];
    float v[16] = {ra0.x, ra0.y, ra0.z, ra0.w, ra1.x, ra1.y, ra1.z, ra1.w,
                   ra2.x, ra2.y, ra2.z, ra2.w, ra3.x, ra3.y, ra3.z, ra3.w};
    #pragma unroll
    for (int j = 0; j < 16; ++j) {
      unsigned short h = bf16_rne(v[j]);
      hb[j] = (short)h;
      lb[j] = (short)bf16_rne(v[j] - bf16_f32(h));
    }
    short* ah = sAh[b] + arow * PA + akh;
    *(s16x8*)(ah) = *(const s16x8*)(hb);
    *(s16x8*)(ah + 8) = *(const s16x8*)(hb + 8);
    short* al = sAl[b] + arow * PA + akh;
    *(s16x8*)(al) = *(const s16x8*)(lb);
    *(s16x8*)(al + 8) = *(const s16x8*)(lb + 8);
  };

  f32x4 acc[2][4];
  #pragma unroll
  for (int rt = 0; rt < 2; ++rt)
    #pragma unroll
    for (int ct = 0; ct < 4; ++ct) acc[rt][ct] = (f32x4){0.f, 0.f, 0.f, 0.f};

  loadA(0); writeLDS(0);
  __syncthreads();

  #pragma unroll 1
  for (int c = 0; c < KC; ++c) {
    if (c + 1 < KC) loadA(c + 1);                     // issue early (T14)
    const int b = c & 1;
    const int aoff0 = (wv * 32 + l15) * PA + l4 * 8;
    const int aoff1 = aoff0 + 16 * PA;
    s16x8 a0h = *(const s16x8*)(sAh[b] + aoff0);
    s16x8 a0l = *(const s16x8*)(sAl[b] + aoff0);
    s16x8 a1h = *(const s16x8*)(sAh[b] + aoff1);
    s16x8 a1l = *(const s16x8*)(sAl[b] + aoff1);
    #pragma unroll
    for (int ct = 0; ct < 4; ++ct) {
      const size_t bo = (size_t)(ct * 16) * KP + c * 32 + wb;
      s16x8 bh = *(const s16x8*)(Whi + bo);           // L2-resident broadcast
      s16x8 bl = *(const s16x8*)(Wlo + bo);
      acc[0][ct] = __builtin_amdgcn_mfma_f32_16x16x32_bf16(a0h, bh, acc[0][ct], 0, 0, 0);
      acc[0][ct] = __builtin_amdgcn_mfma_f32_16x16x32_bf16(a0l, bh, acc[0][ct], 0, 0, 0);
      acc[0][ct] = __builtin_amdgcn_mfma_f32_16x16x32_bf16(a0h, bl, acc[0][ct], 0, 0, 0);
      acc[1][ct] = __builtin_amdgcn_mfma_f32_16x16x32_bf16(a1h, bh, acc[1][ct], 0, 0, 0);
      acc[1][ct] = __builtin_amdgcn_mfma_f32_16x16x32_bf16(a1l, bh, acc[1][ct], 0, 0, 0);
      acc[1][ct] = __builtin_amdgcn_mfma_f32_16x16x32_bf16(a1h, bl, acc[1][ct], 0, 0, 0);
    }
    if (c + 1 < KC) { writeLDS((c + 1) & 1); __syncthreads(); }
  }

  const int rb = gbase + wv * 32;
  #pragma unroll
  for (int rt = 0; rt < 2; ++rt) {
    #pragma unroll
    for (int j = 0; j < 4; ++j) {
      int row = rb + rt * 16 + l4 * 4 + j;
      if (row < N) {
        float d = disv[row];
        unsigned short* yp = Y + ((size_t)row << 6) + l15;
        yp[0]  = bf16_rne(acc[rt][0][j] * d);
        yp[16] = bf16_rne(acc[rt][1][j] * d);
        yp[32] = bf16_rne(acc[rt][2][j] * d);
        yp[48] = bf16_rne(acc[rt][3][j] * d);
      }
    }
  }
}

// ---------------- agg: two nodes per wave (doubles gathers in flight; r15 lesson:
// concurrency, not locality, is the agg currency) ------------------------------------
__launch_bounds__(256)
__global__ void k_agg(const unsigned short* __restrict__ G, const int* __restrict__ offs,
                      const int* __restrict__ csr, const float* __restrict__ dis,
                      const float* __restrict__ bias, float* __restrict__ H, int N) {
  const int lane = threadIdx.x & 63;
  const int n0 = blockIdx.x * 8 + (threadIdx.x >> 6) * 2;   // n0 even
  if (n0 >= N) return;
  const unsigned short* Gl = G + lane;
  int b0 = offs[n0];
  int m0 = offs[n0 + 1];
  int e1 = offs[n0 + 2];          // n0+1 < N always (N even, n0 even)
  int b1 = m0;
  float a0 = bf16_f32(Gl[(size_t)n0 << 6]);
  float a1 = bf16_f32(Gl[(size_t)(n0 + 1) << 6]);
  while (b0 + 8 <= m0 && b1 + 8 <= e1) {     // joint: 16 independent gathers in flight
    int s0[8], s1[8];
    #pragma unroll
    for (int j = 0; j < 8; ++j) s0[j] = csr[b0 + j];
    #pragma unroll
    for (int j = 0; j < 8; ++j) s1[j] = csr[b1 + j];
    float g0[8], g1[8];
    #pragma unroll
    for (int j = 0; j < 8; ++j) g0[j] = bf16_f32(Gl[(size_t)s0[j] << 6]);
    #pragma unroll
    for (int j = 0; j < 8; ++j) g1[j] = bf16_f32(Gl[(size_t)s1[j] << 6]);
    #pragma unroll
    for (int j = 0; j < 8; ++j) a0 += g0[j];
    #pragma unroll
    for (int j = 0; j < 8; ++j) a1 += g1[j];
    b0 += 8; b1 += 8;
  }
  for (; b0 + 8 <= m0; b0 += 8) {
    int s[8];
    #pragma unroll
    for (int j = 0; j < 8; ++j) s[j] = csr[b0 + j];
    float g[8];
    #pragma unroll
    for (int j = 0; j < 8; ++j) g[j] = bf16_f32(Gl[(size_t)s[j] << 6]);
    #pragma unroll
    for (int j = 0; j < 8; ++j) a0 += g[j];
  }
  for (; b0 < m0; ++b0) a0 += bf16_f32(Gl[(size_t)csr[b0] << 6]);
  for (; b1 + 8 <= e1; b1 += 8) {
    int s[8];
    #pragma unroll
    for (int j = 0; j < 8; ++j) s[j] = csr[b1 + j];
    float g[8];
    #pragma unroll
    for (int j = 0; j < 8; ++j) g[j] = bf16_f32(Gl[(size_t)s[j] << 6]);
    #pragma unroll
    for (int j = 0; j < 8; ++j) a1 += g[j];
  }
  for (; b1 < e1; ++b1) a1 += bf16_f32(Gl[(size_t)csr[b1] << 6]);

  a0 = a0 * dis[n0] + bias[lane];
  H[((size_t)n0 << 6) + lane] = (a0 > 0.f) ? a0 : SLOPE * a0;
  a1 = a1 * dis[n0 + 1] + bias[lane];
  H[((size_t)(n0 + 1) << 6) + lane] = (a1 > 0.f) ? a1 : SLOPE * a1;
}

// One wave per graph: mean-pool + fc1 + lrelu + fc2
__launch_bounds__(64)
__global__ void k_pool(const float* __restrict__ H, const int* __restrict__ batch,
                       const float* __restrict__ f1W, const float* __restrict__ f1b,
                       const float* __restrict__ f2W, const float* __restrict__ f2b,
                       float* __restrict__ out, int N) {
  int g = blockIdx.x;
  int lane = threadIdx.x;
  int lo = 0, hi = N;
  while (lo < hi) { int m = (lo + hi) >> 1; if (batch[m] < g) lo = m + 1; else hi = m; }
  int beg = lo;
  hi = N;
  while (lo < hi) { int m = (lo + hi) >> 1; if (batch[m] < g + 1) lo = m + 1; else hi = m; }
  int end = lo;
  float acc = 0.f;
  for (int r = beg; r < end; ++r) acc += H[(size_t)r * 64 + lane];
  float c = (float)(end - beg);
  acc /= (c < 1.f ? 1.f : c);
  __shared__ float p[64];
  p[lane] = acc;
  __syncthreads();
  float q = f1b[lane];
  #pragma unroll
  for (int k = 0; k < 64; ++k) q += p[k] * f1W[k * 64 + lane];
  q = (q > 0.f) ? q : SLOPE * q;
  float v = q * f2W[lane];
  #pragma unroll
  for (int off = 32; off > 0; off >>= 1) v += __shfl_down(v, off, 64);
  if (lane == 0) out[g] = v + f2b[0];
}

extern "C" void kernel_launch(void* const* d_in, const int* in_sizes, int n_in,
                              void* d_out, int out_size, void* d_ws, size_t ws_size,
                              hipStream_t stream) {
  const float* x    = (const float*)d_in[0];
  const int*  eidx  = (const int*)d_in[1];
  const int*  batch = (const int*)d_in[2];
  const float* W0 = (const float*)d_in[3];
  const float* b0 = (const float*)d_in[4];
  const float* W1 = (const float*)d_in[5];
  const float* b1 = (const float*)d_in[6];
  const float* W2 = (const float*)d_in[7];
  const float* b2 = (const float*)d_in[8];
  const float* f1W = (const float*)d_in[9];
  const float* f1b = (const float*)d_in[10];
  const float* f2W = (const float*)d_in[11];
  const float* f2b = (const float*)d_in[12];
  float* out = (float*)d_out;

  const int N = NN, E = NE;
  const int* src  = eidx;
  const int* dstp = eidx + E;

  const size_t NPAD = 100096;   // 782*128 rows exactly
  char* w = (char*)d_ws;
  float* H     = (float*)w; w += NPAD * 64 * 4;                // fp32 layer buffer
  unsigned short* G = (unsigned short*)w; w += NPAD * 64 * 2;  // bf16 gemm output
  int*   csr   = (int*)w;   w += (size_t)E * 4;
  int*   offs  = (int*)w;   w += (size_t)(N + 4) * 4;
  float* dis   = (float*)w; w += (size_t)N * 4;
  int*   bh    = (int*)w;   w += (size_t)NBLK * NBUK * 4;
  int*   btot  = (int*)w;   w += (NBUK + 1) * 4;
  int*   boffs = (int*)w;   w += (NBUK + 4) * 4;
  short* wt0h  = (short*)w; w += 64 * 192 * 2;
  short* wt0l  = (short*)w; w += 64 * 192 * 2;
  short* wt1h  = (short*)w; w += 64 * 64 * 2;
  short* wt1l  = (short*)w; w += 64 * 64 * 2;
  short* wt2h  = (short*)w; w += 64 * 64 * 2;
  short* wt2l  = (short*)w; w += 64 * 64 * 2;
  unsigned* bedge = (unsigned*)H;   // bedge dead before first agg writes H

  k_wsplit<<<48, 256, 0, stream>>>(W0, wt0h, wt0l, NODE_IN, 192);
  k_wsplit<<<16, 256, 0, stream>>>(W1, wt1h, wt1l, 64, 64);
  k_wsplit<<<16, 256, 0, stream>>>(W2, wt2h, wt2l, 64, 64);

  k_hist<<<NBLK, 256, 0, stream>>>(dstp, bh, E);
  k_bucket_scan<<<NBUK, 256, 0, stream>>>(bh, btot);
  k_btot_scan<<<1, 512, 0, stream>>>(btot, boffs, E);
  k_scatter<<<NBLK, 256, 0, stream>>>(src, dstp, bh, boffs, bedge, E);
  k_b2csr<<<NBUK, 256, 0, stream>>>(bedge, boffs, offs, dis, csr, N);

  const int NTB = (N + 127) / 128;   // 782
  k_gemm<NODE_IN, 192><<<NTB, 256, 0, stream>>>(x, wt0h, wt0l, dis, G, N);
  k_agg<<<(N + 7) / 8, 256, 0, stream>>>(G, offs, csr, dis, b0, H, N);
  k_gemm<64, 64><<<NTB, 256, 0, stream>>>(H, wt1h, wt1l, dis, G, N);
  k_agg<<<(N + 7) / 8, 256, 0, stream>>>(G, offs, csr, dis, b1, H, N);
  k_gemm<64, 64><<<NTB, 256, 0, stream>>>(H, wt2h, wt2l, dis, G, N);
  k_agg<<<(N + 7) / 8, 256, 0, stream>>>(G, offs, csr, dis, b2, H, N);
  k_pool<<<NG, 64, 0, stream>>>(H, batch, f1W, f1b, f2W, f2b, out, N);
}

// Round 17
// 308.590 us; speedup vs baseline: 7.2988x; 1.1279x over previous
//
#include <hip/hip_runtime.h>

#define NN 100000
#define NE 1600000
#define NG 1024
#define NODE_IN 163
#define SLOPE 0.01f
#define NBUK 391
#define BUKSH 8
#define EPB 8192
#define NBLK ((NE + EPB - 1) / EPB)

typedef short s16x8 __attribute__((ext_vector_type(8)));
typedef float f32x4 __attribute__((ext_vector_type(4)));

__device__ __forceinline__ unsigned short bf16_rne(float x) {
  unsigned u = __float_as_uint(x);
  return (unsigned short)((u + 0x7FFFu + ((u >> 16) & 1u)) >> 16);
}
__device__ __forceinline__ float bf16_f32(unsigned short h) {
  return __uint_as_float(((unsigned)h) << 16);
}

// ---------------- CSR build (privatized counting sort; rounds 4-14, verified) ---------
__global__ void k_hist(const int* __restrict__ dst, int* __restrict__ bh, int E) {
  __shared__ int h[NBUK];
  for (int i = threadIdx.x; i < NBUK; i += 256) h[i] = 0;
  __syncthreads();
  int beg = blockIdx.x * EPB, end = min(E, beg + EPB);
  for (int e = beg + threadIdx.x; e < end; e += 256) atomicAdd(&h[dst[e] >> BUKSH], 1);
  __syncthreads();
  for (int i = threadIdx.x; i < NBUK; i += 256) bh[blockIdx.x * NBUK + i] = h[i];
}

__global__ void k_bucket_scan(int* __restrict__ bh, int* __restrict__ btot) {
  __shared__ int s[256];
  int bucket = blockIdx.x, tid = threadIdx.x;
  int v = (tid < NBLK) ? bh[tid * NBUK + bucket] : 0;
  s[tid] = v;
  __syncthreads();
  for (int off = 1; off < 256; off <<= 1) {
    int t = (tid >= off) ? s[tid - off] : 0;
    __syncthreads();
    s[tid] += t;
    __syncthreads();
  }
  if (tid < NBLK) bh[tid * NBUK + bucket] = s[tid] - v;
  if (tid == 255) btot[bucket] = s[255];
}

__global__ void k_btot_scan(const int* __restrict__ btot, int* __restrict__ boffs, int E) {
  __shared__ int s[512];
  int tid = threadIdx.x;
  int v = (tid < NBUK) ? btot[tid] : 0;
  s[tid] = v;
  __syncthreads();
  for (int off = 1; off < 512; off <<= 1) {
    int t = (tid >= off) ? s[tid - off] : 0;
    __syncthreads();
    s[tid] += t;
    __syncthreads();
  }
  if (tid < NBUK) boffs[tid] = s[tid] - v;
  if (tid == 0) boffs[NBUK] = E;
}

__global__ void k_scatter(const int* __restrict__ src, const int* __restrict__ dst,
                          const int* __restrict__ bh, const int* __restrict__ boffs,
                          unsigned* __restrict__ bedge, int E) {
  __shared__ int cur[NBUK];
  for (int i = threadIdx.x; i < NBUK; i += 256)
    cur[i] = boffs[i] + bh[blockIdx.x * NBUK + i];
  __syncthreads();
  int beg = blockIdx.x * EPB, end = min(E, beg + EPB);
  for (int e = beg + threadIdx.x; e < end; e += 256) {
    int d = dst[e];
    int pos = atomicAdd(&cur[d >> BUKSH], 1);
    bedge[pos] = (unsigned)src[e] | ((unsigned)(d & 255) << 17);
  }
}

__global__ void k_b2csr(const unsigned* __restrict__ bedge, const int* __restrict__ boffs,
                        int* __restrict__ offs, float* __restrict__ dis,
                        int* __restrict__ csr, int N) {
  __shared__ int lcnt[256];
  __shared__ int s[256];
  __shared__ int lcur[256];
  int b = blockIdx.x, tid = threadIdx.x;
  int beg = boffs[b], end = boffs[b + 1];
  lcnt[tid] = 0;
  __syncthreads();
  for (int e = beg + tid; e < end; e += 256) atomicAdd(&lcnt[bedge[e] >> 17], 1);
  __syncthreads();
  int v = lcnt[tid];
  s[tid] = v;
  __syncthreads();
  for (int off = 1; off < 256; off <<= 1) {
    int t = (tid >= off) ? s[tid - off] : 0;
    __syncthreads();
    s[tid] += t;
    __syncthreads();
  }
  int o = s[tid] - v;
  int node = (b << BUKSH) + tid;
  if (node <= N) offs[node] = beg + o;
  if (node < N) dis[node] = rsqrtf((float)(v + 1));
  lcur[tid] = o;
  __syncthreads();
  for (int e = beg + tid; e < end; e += 256) {
    unsigned w = bedge[e];
    int p = atomicAdd(&lcur[w >> 17], 1);
    csr[beg + p] = (int)(w & 0x1FFFFu);
  }
}

// ---------------- W pre-split: W[K][64] fp32 -> Wt_hi/lo[64][KP] bf16 (transposed) ----
__global__ void k_wsplit(const float* __restrict__ W, short* __restrict__ hi,
                         short* __restrict__ lo, int K, int KP) {
  int idx = blockIdx.x * 256 + threadIdx.x;
  if (idx >= 64 * KP) return;
  int c = idx / KP, kk = idx - c * KP;
  float v = (kk < K) ? W[(size_t)kk * 64 + c] : 0.f;
  unsigned short h = bf16_rne(v);
  hi[idx] = (short)h;
  lo[idx] = (short)bf16_rne(v - bf16_f32(h));
}

// ---------------- GEMM via MFMA split-bf16 (round-14 proven: A+B staged in LDS) -------
template<int K, int KP>
__launch_bounds__(256)
__global__ void k_gemm(const float* __restrict__ X, const short* __restrict__ Whi,
                       const short* __restrict__ Wlo, const float* __restrict__ disv,
                       unsigned short* __restrict__ Y, int N) {
  constexpr int KC = KP / 32;
  constexpr int PA = 40;
  constexpr int PB = 40;
  __shared__ __align__(16) short sAh[2][128 * PA];
  __shared__ __align__(16) short sAl[2][128 * PA];
  __shared__ __align__(16) short sBh[2][64 * PB];
  __shared__ __align__(16) short sBl[2][64 * PB];

  const int tid = threadIdx.x;
  const int lane = tid & 63, wv = tid >> 6;
  const int l15 = lane & 15, l4 = lane >> 4;
  const int gbase = blockIdx.x << 7;

  const int arow = tid >> 1, akh = (tid & 1) << 4;
  int grow = gbase + arow;
  if (K != KP) grow = min(grow, N - 1);
  const float* xr = X + (size_t)grow * K;
  const int bcol = tid >> 2, bk8 = (tid & 3) << 3;

  float4 ra0, ra1, ra2, ra3;
  s16x8 rbh, rbl;

  auto loadA = [&](int c) {
    if (K != KP && c == KC - 1) {
      ra0 = ra1 = ra2 = ra3 = make_float4(0.f, 0.f, 0.f, 0.f);
      if (akh == 0) { ra0.x = xr[160]; ra0.y = xr[161]; ra0.z = xr[162]; }
    } else {
      const float* p = xr + c * 32 + akh;
      ra0 = *(const float4*)(p);
      ra1 = *(const float4*)(p + 4);
      ra2 = *(const float4*)(p + 8);
      ra3 = *(const float4*)(p + 12);
    }
  };
  auto loadB = [&](int c) {
    const size_t o = (size_t)bcol * KP + c * 32 + bk8;
    rbh = *(const s16x8*)(Whi + o);
    rbl = *(const s16x8*)(Wlo + o);
  };
  auto writeLDS = [&](int b) {
    short hb[16], lb[16];
    float v[16] = {ra0.x, ra0.y, ra0.z, ra0.w, ra1.x, ra1.y, ra1.z, ra1.w,
                   ra2.x, ra2.y, ra2.z, ra2.w, ra3.x, ra3.y, ra3.z, ra3.w};
    #pragma unroll
    for (int j = 0; j < 16; ++j) {
      unsigned short h = bf16_rne(v[j]);
      hb[j] = (short)h;
      lb[j] = (short)bf16_rne(v[j] - bf16_f32(h));
    }
    short* ah = sAh[b] + arow * PA + akh;
    *(s16x8*)(ah) = *(const s16x8*)(hb);
    *(s16x8*)(ah + 8) = *(const s16x8*)(hb + 8);
    short* al = sAl[b] + arow * PA + akh;
    *(s16x8*)(al) = *(const s16x8*)(lb);
    *(s16x8*)(al + 8) = *(const s16x8*)(lb + 8);
    *(s16x8*)(sBh[b] + bcol * PB + bk8) = rbh;
    *(s16x8*)(sBl[b] + bcol * PB + bk8) = rbl;
  };

  f32x4 acc[2][4];
  #pragma unroll
  for (int rt = 0; rt < 2; ++rt)
    #pragma unroll
    for (int ct = 0; ct < 4; ++ct) acc[rt][ct] = (f32x4){0.f, 0.f, 0.f, 0.f};

  loadA(0); loadB(0); writeLDS(0);
  __syncthreads();

  #pragma unroll 1
  for (int c = 0; c < KC; ++c) {
    if (c + 1 < KC) { loadA(c + 1); loadB(c + 1); }   // issue early (T14)
    const int b = c & 1;
    const int aoff0 = (wv * 32 + l15) * PA + l4 * 8;
    const int aoff1 = aoff0 + 16 * PA;
    s16x8 a0h = *(const s16x8*)(sAh[b] + aoff0);
    s16x8 a0l = *(const s16x8*)(sAl[b] + aoff0);
    s16x8 a1h = *(const s16x8*)(sAh[b] + aoff1);
    s16x8 a1l = *(const s16x8*)(sAl[b] + aoff1);
    #pragma unroll
    for (int ct = 0; ct < 4; ++ct) {
      const int boff = (ct * 16 + l15) * PB + l4 * 8;
      s16x8 bh = *(const s16x8*)(sBh[b] + boff);
      s16x8 bl = *(const s16x8*)(sBl[b] + boff);
      acc[0][ct] = __builtin_amdgcn_mfma_f32_16x16x32_bf16(a0h, bh, acc[0][ct], 0, 0, 0);
      acc[0][ct] = __builtin_amdgcn_mfma_f32_16x16x32_bf16(a0l, bh, acc[0][ct], 0, 0, 0);
      acc[0][ct] = __builtin_amdgcn_mfma_f32_16x16x32_bf16(a0h, bl, acc[0][ct], 0, 0, 0);
      acc[1][ct] = __builtin_amdgcn_mfma_f32_16x16x32_bf16(a1h, bh, acc[1][ct], 0, 0, 0);
      acc[1][ct] = __builtin_amdgcn_mfma_f32_16x16x32_bf16(a1l, bh, acc[1][ct], 0, 0, 0);
      acc[1][ct] = __builtin_amdgcn_mfma_f32_16x16x32_bf16(a1h, bl, acc[1][ct], 0, 0, 0);
    }
    if (c + 1 < KC) { writeLDS((c + 1) & 1); __syncthreads(); }
  }

  const int rb = gbase + wv * 32;
  #pragma unroll
  for (int rt = 0; rt < 2; ++rt) {
    #pragma unroll
    for (int j = 0; j < 4; ++j) {
      int row = rb + rt * 16 + l4 * 4 + j;
      if (row < N) {
        float d = disv[row];
        unsigned short* yp = Y + ((size_t)row << 6) + l15;
        yp[0]  = bf16_rne(acc[rt][0][j] * d);
        yp[16] = bf16_rne(acc[rt][1][j] * d);
        yp[32] = bf16_rne(acc[rt][2][j] * d);
        yp[48] = bf16_rne(acc[rt][3][j] * d);
      }
    }
  }
}

// ---------------- agg: quad-row gathers (4x fewer VMEM instructions) ------------------
// Wave per node. lane: g=lane>>4 (edge slot), p=lane&15 (feature quad).
// Per 16 edges: 4 csr loads (uniform in group) + 4 ushort4 gathers (each instr reads
// 4 rows x 128B). Round-16 evidence: time invariant under bytes/2 and inflight x2 ->
// VMEM-instruction-rate bound; this cuts instructions ~4x (2/edge -> 0.5/edge).
__launch_bounds__(256)
__global__ void k_agg(const unsigned short* __restrict__ G, const int* __restrict__ offs,
                      const int* __restrict__ csr, const float* __restrict__ dis,
                      const float* __restrict__ bias, float* __restrict__ H, int N) {
  int node = blockIdx.x * 4 + (threadIdx.x >> 6);
  if (node >= N) return;
  const int lane = threadIdx.x & 63;
  const int g = lane >> 4, p = lane & 15;
  const ushort4* G4 = (const ushort4*)G;     // 16 quads per row
  int beg = offs[node], end = offs[node + 1];
  float ax = 0.f, ay = 0.f, az = 0.f, aw = 0.f;
  int e = beg + g;
  for (; e + 12 < end; e += 16) {            // 4 edges for this slot, all valid
    int s0 = csr[e], s1 = csr[e + 4], s2 = csr[e + 8], s3 = csr[e + 12];
    ushort4 v0 = G4[(size_t)s0 * 16 + p];
    ushort4 v1 = G4[(size_t)s1 * 16 + p];
    ushort4 v2 = G4[(size_t)s2 * 16 + p];
    ushort4 v3 = G4[(size_t)s3 * 16 + p];
    ax += bf16_f32(v0.x) + bf16_f32(v1.x) + bf16_f32(v2.x) + bf16_f32(v3.x);
    ay += bf16_f32(v0.y) + bf16_f32(v1.y) + bf16_f32(v2.y) + bf16_f32(v3.y);
    az += bf16_f32(v0.z) + bf16_f32(v1.z) + bf16_f32(v2.z) + bf16_f32(v3.z);
    aw += bf16_f32(v0.w) + bf16_f32(v1.w) + bf16_f32(v2.w) + bf16_f32(v3.w);
  }
  for (; e < end; e += 4) {                  // per-slot tail, stride 4
    int s = csr[e];
    ushort4 v = G4[(size_t)s * 16 + p];
    ax += bf16_f32(v.x); ay += bf16_f32(v.y);
    az += bf16_f32(v.z); aw += bf16_f32(v.w);
  }
  // butterfly across the 4 slots (xor 16, 32)
  #pragma unroll
  for (int off = 16; off < 64; off <<= 1) {
    ax += __shfl_xor(ax, off, 64);
    ay += __shfl_xor(ay, off, 64);
    az += __shfl_xor(az, off, 64);
    aw += __shfl_xor(aw, off, 64);
  }
  if (g == 0) {                              // lanes 0-15: self + dis + bias + lrelu
    ushort4 sv = G4[(size_t)node * 16 + p];
    float d = dis[node];
    float4 bq = ((const float4*)bias)[p];
    float ox = (ax + bf16_f32(sv.x)) * d + bq.x;
    float oy = (ay + bf16_f32(sv.y)) * d + bq.y;
    float oz = (az + bf16_f32(sv.z)) * d + bq.z;
    float ow = (aw + bf16_f32(sv.w)) * d + bq.w;
    ox = (ox > 0.f) ? ox : SLOPE * ox;
    oy = (oy > 0.f) ? oy : SLOPE * oy;
    oz = (oz > 0.f) ? oz : SLOPE * oz;
    ow = (ow > 0.f) ? ow : SLOPE * ow;
    ((float4*)(H + ((size_t)node << 6)))[p] = make_float4(ox, oy, oz, ow);
  }
}

// One wave per graph: mean-pool + fc1 + lrelu + fc2
__launch_bounds__(64)
__global__ void k_pool(const float* __restrict__ H, const int* __restrict__ batch,
                       const float* __restrict__ f1W, const float* __restrict__ f1b,
                       const float* __restrict__ f2W, const float* __restrict__ f2b,
                       float* __restrict__ out, int N) {
  int g = blockIdx.x;
  int lane = threadIdx.x;
  int lo = 0, hi = N;
  while (lo < hi) { int m = (lo + hi) >> 1; if (batch[m] < g) lo = m + 1; else hi = m; }
  int beg = lo;
  hi = N;
  while (lo < hi) { int m = (lo + hi) >> 1; if (batch[m] < g + 1) lo = m + 1; else hi = m; }
  int end = lo;
  float acc = 0.f;
  for (int r = beg; r < end; ++r) acc += H[(size_t)r * 64 + lane];
  float c = (float)(end - beg);
  acc /= (c < 1.f ? 1.f : c);
  __shared__ float p[64];
  p[lane] = acc;
  __syncthreads();
  float q = f1b[lane];
  #pragma unroll
  for (int k = 0; k < 64; ++k) q += p[k] * f1W[k * 64 + lane];
  q = (q > 0.f) ? q : SLOPE * q;
  float v = q * f2W[lane];
  #pragma unroll
  for (int off = 32; off > 0; off >>= 1) v += __shfl_down(v, off, 64);
  if (lane == 0) out[g] = v + f2b[0];
}

extern "C" void kernel_launch(void* const* d_in, const int* in_sizes, int n_in,
                              void* d_out, int out_size, void* d_ws, size_t ws_size,
                              hipStream_t stream) {
  const float* x    = (const float*)d_in[0];
  const int*  eidx  = (const int*)d_in[1];
  const int*  batch = (const int*)d_in[2];
  const float* W0 = (const float*)d_in[3];
  const float* b0 = (const float*)d_in[4];
  const float* W1 = (const float*)d_in[5];
  const float* b1 = (const float*)d_in[6];
  const float* W2 = (const float*)d_in[7];
  const float* b2 = (const float*)d_in[8];
  const float* f1W = (const float*)d_in[9];
  const float* f1b = (const float*)d_in[10];
  const float* f2W = (const float*)d_in[11];
  const float* f2b = (const float*)d_in[12];
  float* out = (float*)d_out;

  const int N = NN, E = NE;
  const int* src  = eidx;
  const int* dstp = eidx + E;

  const size_t NPAD = 100096;   // 782*128 rows exactly
  char* w = (char*)d_ws;
  float* H     = (float*)w; w += NPAD * 64 * 4;                // fp32 layer buffer
  unsigned short* G = (unsigned short*)w; w += NPAD * 64 * 2;  // bf16 gemm output
  int*   csr   = (int*)w;   w += (size_t)E * 4;
  int*   offs  = (int*)w;   w += (size_t)(N + 4) * 4;
  float* dis   = (float*)w; w += (size_t)N * 4;
  int*   bh    = (int*)w;   w += (size_t)NBLK * NBUK * 4;
  int*   btot  = (int*)w;   w += (NBUK + 1) * 4;
  int*   boffs = (int*)w;   w += (NBUK + 4) * 4;
  short* wt0h  = (short*)w; w += 64 * 192 * 2;
  short* wt0l  = (short*)w; w += 64 * 192 * 2;
  short* wt1h  = (short*)w; w += 64 * 64 * 2;
  short* wt1l  = (short*)w; w += 64 * 64 * 2;
  short* wt2h  = (short*)w; w += 64 * 64 * 2;
  short* wt2l  = (short*)w; w += 64 * 64 * 2;
  unsigned* bedge = (unsigned*)H;   // bedge dead before first agg writes H

  k_wsplit<<<48, 256, 0, stream>>>(W0, wt0h, wt0l, NODE_IN, 192);
  k_wsplit<<<16, 256, 0, stream>>>(W1, wt1h, wt1l, 64, 64);
  k_wsplit<<<16, 256, 0, stream>>>(W2, wt2h, wt2l, 64, 64);

  k_hist<<<NBLK, 256, 0, stream>>>(dstp, bh, E);
  k_bucket_scan<<<NBUK, 256, 0, stream>>>(bh, btot);
  k_btot_scan<<<1, 512, 0, stream>>>(btot, boffs, E);
  k_scatter<<<NBLK, 256, 0, stream>>>(src, dstp, bh, boffs, bedge, E);
  k_b2csr<<<NBUK, 256, 0, stream>>>(bedge, boffs, offs, dis, csr, N);

  const int NTB = (N + 127) / 128;   // 782
  k_gemm<NODE_IN, 192><<<NTB, 256, 0, stream>>>(x, wt0h, wt0l, dis, G, N);
  k_agg<<<(N + 3) / 4, 256, 0, stream>>>(G, offs, csr, dis, b0, H, N);
  k_gemm<64, 64><<<NTB, 256, 0, stream>>>(H, wt1h, wt1l, dis, G, N);
  k_agg<<<(N + 3) / 4, 256, 0, stream>>>(G, offs, csr, dis, b1, H, N);
  k_gemm<64, 64><<<NTB, 256, 0, stream>>>(H, wt2h, wt2l, dis, G, N);
  k_agg<<<(N + 3) / 4, 256, 0, stream>>>(G, offs, csr, dis, b2, H, N);
  k_pool<<<NG, 64, 0, stream>>>(H, batch, f1W, f1b, f2W, f2b, out, N);
}